// Round 6
// baseline (437.730 us; speedup 1.0000x reference)
//
#include <hip/hip_runtime.h>
#include <hip/hip_bf16.h>
#include <math.h>
#include <stdint.h>

#define B_    32
#define S_    512
#define H_    768
#define NH_   12
#define HD_   64
#define NCOL_ 32
#define M_    (B_*S_)   // 16384

typedef __bf16 bf16;
typedef __bf16 bf16x8 __attribute__((ext_vector_type(8)));
typedef __bf16 bf16x4 __attribute__((ext_vector_type(4)));
typedef float  f32x4  __attribute__((ext_vector_type(4)));

// ---------------------------------------------------------------------------
// async global->LDS 16B copy (global_load_lds_dwordx4)
// ---------------------------------------------------------------------------
__device__ __forceinline__ void async_load16(const void* g, void* l) {
    __builtin_amdgcn_global_load_lds(
        (__attribute__((address_space(1))) unsigned int*)g,
        (__attribute__((address_space(3))) unsigned int*)l, 16, 0, 0);
}

// fp32 -> bf16x8 converting load (32B in)
__device__ __forceinline__ bf16x8 cvt8(const float* p) {
    const float4* fp = (const float4*)p;
    float4 x = fp[0], y = fp[1];
    bf16x8 r;
    r[0] = (bf16)x.x; r[1] = (bf16)x.y; r[2] = (bf16)x.z; r[3] = (bf16)x.w;
    r[4] = (bf16)y.x; r[5] = (bf16)y.y; r[6] = (bf16)y.z; r[7] = (bf16)y.w;
    return r;
}

// ---------------------------------------------------------------------------
// convert hidden -> hbf (bf16) and gathered column embeds -> hcol (bf16)
// ---------------------------------------------------------------------------
__global__ __launch_bounds__(256) void cvt_x_kernel(
    const float* __restrict__ hidden, const float* __restrict__ ce,
    const int* __restrict__ cc, const int* __restrict__ vm,
    bf16* __restrict__ hbf, bf16* __restrict__ hcol)
{
    int id = blockIdx.x * 256 + threadIdx.x;
    if (id < M_ * 96) {
        int row = id / 96, c = id - row * 96;
        *(bf16x8*)&hbf[(long)row * H_ + c * 8] = cvt8(hidden + (long)row * H_ + c * 8);
    } else {
        int cid = id - M_ * 96;
        int row = cid / 96, c = cid - row * 96;
        int b = row >> 9;
        int m = vm[row];
        bf16x8 val;
#pragma unroll
        for (int i = 0; i < 8; i++) val[i] = (bf16)0.0f;
        if (m > 0) {
            int col = m - 1;
            if (cc[b * NCOL_ + col] == 1)
                val = cvt8(ce + ((long)(b * NCOL_ + col)) * H_ + c * 8);
        }
        *(bf16x8*)&hcol[(long)row * H_ + c * 8] = val;
    }
}

// ---------------------------------------------------------------------------
// convert weights -> wpack (order: Wd,Wc,Wq,Wk,Wv,Wo) + packed qkv bias
// ---------------------------------------------------------------------------
__global__ __launch_bounds__(256) void cvt_w_kernel(
    const float* __restrict__ Wd, const float* __restrict__ Wc,
    const float* __restrict__ Wq, const float* __restrict__ Wk,
    const float* __restrict__ Wv, const float* __restrict__ Wo,
    const float* __restrict__ bq, const float* __restrict__ bk,
    const float* __restrict__ bv, bf16* __restrict__ wpack,
    float* __restrict__ bqkv)
{
    int id = blockIdx.x * 256 + threadIdx.x;
    if (id < 442368) {
        const float* src;
        int r = id;
        if      (r < 73728)  { src = Wd; }
        else if (r < 147456) { src = Wc; r -= 73728; }
        else if (r < 221184) { src = Wq; r -= 147456; }
        else if (r < 294912) { src = Wk; r -= 221184; }
        else if (r < 368640) { src = Wv; r -= 294912; }
        else                 { src = Wo; r -= 368640; }
        *(bf16x8*)&wpack[(long)id * 8] = cvt8(src + (long)r * 8);
    } else if (id < 442656) {
        int j0 = (id - 442368) * 8;
#pragma unroll
        for (int i = 0; i < 8; i++) {
            int j = j0 + i;
            float v = (j < 768) ? bq[j] : (j < 1536) ? bk[j - 768] : bv[j - 1536];
            bqkv[j] = v;
        }
    }
}

// ---------------------------------------------------------------------------
// GEMM C[m,n] = sum_k A[m,k]*Bw[n,k]  (+ epilogue per MODE), all bf16, lda=ldb=768
// BK=64 as TWO 32-col panels per iteration (each panel in the verified
// lane-linear global_load_lds layout) -> half the barrier drains per K.
// MODE 0: gelu(acc + bias1[n] + bias2[n]) -> [M,768] bf16
// MODE 1: acc + bias1[n] -> qkv: Q,K sections [B,NH,S,HD]; V section [B,NH,HD,S]
// MODE 2: acc + bias1[n] + resid[m,n] -> [M,768] bf16 (in-place ok)
// KSPLIT must be a multiple of 64.
// ---------------------------------------------------------------------------
template<int MODE>
__global__ __launch_bounds__(256) void gemm_bt(
    const bf16* __restrict__ A0, const bf16* __restrict__ A1,
    const bf16* __restrict__ B0, const bf16* __restrict__ B1,
    const float* __restrict__ bias1, const float* __restrict__ bias2,
    const bf16* __restrict__ resid, bf16* __restrict__ out,
    int K, int KSPLIT)
{
    __shared__ __align__(16) bf16 As[128 * 64];   // 2 panels of 128x32
    __shared__ __align__(16) bf16 Bs[128 * 64];

    const int tid  = threadIdx.x;
    const int lane = tid & 63;
    const int wave = tid >> 6;
    const int wm   = wave & 1;
    const int wn   = wave >> 1;
    const int m0   = blockIdx.x * 128;
    const int n0   = blockIdx.y * 128;

    const int srow = tid >> 2;            // 0..63
    const int scol = (tid & 3) * 8;       // 0,8,16,24

    f32x4 acc[4][4];
    const f32x4 zero4 = {0.f, 0.f, 0.f, 0.f};
#pragma unroll
    for (int i = 0; i < 4; i++)
#pragma unroll
        for (int j = 0; j < 4; j++) acc[i][j] = zero4;

    const int a_off = (wm * 64 + (lane & 15)) * 32 + (lane >> 4) * 8;
    const int b_off = (wn * 64 + (lane & 15)) * 32 + (lane >> 4) * 8;

    for (int k0 = 0; k0 < K; k0 += 64) {
        const bf16* ag;
        const bf16* bg;
        if (k0 < KSPLIT) { ag = A0 + k0; bg = B0 + k0; }
        else             { ag = A1 + (k0 - KSPLIT); bg = B1 + (k0 - KSPLIT); }

        __syncthreads();   // prev iter's LDS reads done
        // panel 0: k-cols [0,32)
        async_load16(ag + (long)(m0 + srow) * H_ + scol,            As + tid * 8);
        async_load16(ag + (long)(m0 + 64 + srow) * H_ + scol,       As + 2048 + tid * 8);
        async_load16(bg + (long)(n0 + srow) * H_ + scol,            Bs + tid * 8);
        async_load16(bg + (long)(n0 + 64 + srow) * H_ + scol,       Bs + 2048 + tid * 8);
        // panel 1: k-cols [32,64)
        async_load16(ag + (long)(m0 + srow) * H_ + 32 + scol,       As + 4096 + tid * 8);
        async_load16(ag + (long)(m0 + 64 + srow) * H_ + 32 + scol,  As + 6144 + tid * 8);
        async_load16(bg + (long)(n0 + srow) * H_ + 32 + scol,       Bs + 4096 + tid * 8);
        async_load16(bg + (long)(n0 + 64 + srow) * H_ + 32 + scol,  Bs + 6144 + tid * 8);
        __syncthreads();   // async copies drained + visible

#pragma unroll
        for (int p = 0; p < 2; p++) {
            const bf16* Ap = As + p * 4096;
            const bf16* Bp = Bs + p * 4096;
            bf16x8 af[4], bfr[4];
#pragma unroll
            for (int i = 0; i < 4; i++) af[i]  = *(const bf16x8*)(Ap + a_off + i * 512);
#pragma unroll
            for (int j = 0; j < 4; j++) bfr[j] = *(const bf16x8*)(Bp + b_off + j * 512);
#pragma unroll
            for (int i = 0; i < 4; i++)
#pragma unroll
                for (int j = 0; j < 4; j++)
                    acc[i][j] = __builtin_amdgcn_mfma_f32_16x16x32_bf16(af[i], bfr[j], acc[i][j], 0, 0, 0);
        }
    }

    const int c_r = (lane >> 4) * 4;
    const int c_c = lane & 15;

    int sec = 0;
    if (MODE == 1) sec = (n0 >= 1536) ? 2 : ((n0 >= 768) ? 1 : 0);
    bf16* dst = (MODE == 1) ? out + (long)sec * M_ * H_ : out;

#pragma unroll
    for (int j = 0; j < 4; j++) {
        const int col = n0 + wn * 64 + j * 16 + c_c;
        float bias = bias1[col];
        if (MODE == 0) bias += bias2[col];
#pragma unroll
        for (int i = 0; i < 4; i++) {
#pragma unroll
            for (int r = 0; r < 4; r++) {
                const int row = m0 + wm * 64 + i * 16 + c_r + r;
                float v = acc[i][j][r] + bias;
                if (MODE == 0) {
                    v = 0.5f * v * (1.0f + erff(v * 0.70710678118654752f));
                    dst[(long)row * H_ + col] = (bf16)v;
                } else if (MODE == 1) {
                    int b = row >> 9, s = row & 511;
                    int cs = col - sec * 768;
                    int head = cs >> 6, d = cs & 63;
                    if (sec == 2)   // V stored transposed: [B,NH,HD,S]
                        dst[(((long)(b * NH_ + head)) * HD_ + d) * S_ + s] = (bf16)v;
                    else
                        dst[(((long)(b * NH_ + head)) * S_ + s) * HD_ + d] = (bf16)v;
                } else {
                    v += (float)resid[(long)row * H_ + col];
                    dst[(long)row * H_ + col] = (bf16)v;
                }
            }
        }
    }
}

// ---------------------------------------------------------------------------
// flash attention, transposed-score form (unchanged from round 5).
// ---------------------------------------------------------------------------
#define QP 72   // LDS row stride (elems) for Qs/Ks/Vt/Ps: 144 B, 16B-aligned

__global__ __launch_bounds__(256) void attn_kernel(
    const bf16* __restrict__ q, const bf16* __restrict__ k,
    const bf16* __restrict__ vt, bf16* __restrict__ ctx)
{
    __shared__ __align__(16) bf16 Qs[64 * QP];
    __shared__ __align__(16) bf16 Ks[64 * QP];
    __shared__ __align__(16) bf16 Vt[64 * QP];      // V^T chunk: [d][t]
    __shared__ __align__(16) bf16 Ps[4][16 * QP];   // per-wave P: [q][t]

    const int tid  = threadIdx.x;
    const int lane = tid & 63;
    const int w    = tid >> 6;
    const int quad = lane >> 4;
    const int ln16 = lane & 15;

    const int bid = blockIdx.x;
    const int qt  = bid / 384;          // qt-major: same g -> same XCD (384%8==0)
    const int g   = bid - qt * 384;
    const int b   = g / 12;
    const int h   = g - b * 12;
    const long base = ((long)(b * NH_ + h)) * S_ * HD_;

    const int r0 = tid >> 2;            // row 0..63
    const int e0 = (tid & 3) * 16;      // col elems 0,16,32,48

    {
        const bf16* qg = q + base + (long)qt * 64 * HD_;
        *(uint4*)&Qs[r0 * QP + e0]     = *(const uint4*)&qg[r0 * HD_ + e0];
        *(uint4*)&Qs[r0 * QP + e0 + 8] = *(const uint4*)&qg[r0 * HD_ + e0 + 8];
    }
    const bf16* kg = k  + base;
    const bf16* vg = vt + base;
    uint4 kr0 = *(const uint4*)&kg[r0 * HD_ + e0];
    uint4 kr1 = *(const uint4*)&kg[r0 * HD_ + e0 + 8];
    uint4 vr0 = *(const uint4*)&vg[(long)r0 * S_ + e0];
    uint4 vr1 = *(const uint4*)&vg[(long)r0 * S_ + e0 + 8];
    __syncthreads();

    const bf16x8 bq0 = *(const bf16x8*)&Qs[(w * 16 + ln16) * QP + quad * 8];
    const bf16x8 bq1 = *(const bf16x8*)&Qs[(w * 16 + ln16) * QP + 32 + quad * 8];

    f32x4 O[4];
    const f32x4 zero4 = {0.f, 0.f, 0.f, 0.f};
#pragma unroll
    for (int t = 0; t < 4; t++) O[t] = zero4;
    float mo = -1e30f, l = 0.f;

    for (int kc = 0; kc < 8; kc++) {
        __syncthreads();
        *(uint4*)&Ks[r0 * QP + e0]     = kr0;
        *(uint4*)&Ks[r0 * QP + e0 + 8] = kr1;
        *(uint4*)&Vt[r0 * QP + e0]     = vr0;
        *(uint4*)&Vt[r0 * QP + e0 + 8] = vr1;
        {
            int kcn = (kc < 7) ? kc + 1 : 7;
            kr0 = *(const uint4*)&kg[(long)kcn * 64 * HD_ + r0 * HD_ + e0];
            kr1 = *(const uint4*)&kg[(long)kcn * 64 * HD_ + r0 * HD_ + e0 + 8];
            vr0 = *(const uint4*)&vg[(long)r0 * S_ + kcn * 64 + e0];
            vr1 = *(const uint4*)&vg[(long)r0 * S_ + kcn * 64 + e0 + 8];
        }
        __syncthreads();

        f32x4 sc[4];
#pragma unroll
        for (int i = 0; i < 4; i++) {
            bf16x8 a0 = *(const bf16x8*)&Ks[(i * 16 + ln16) * QP + quad * 8];
            bf16x8 a1 = *(const bf16x8*)&Ks[(i * 16 + ln16) * QP + 32 + quad * 8];
            sc[i] = zero4;
            sc[i] = __builtin_amdgcn_mfma_f32_16x16x32_bf16(a0, bq0, sc[i], 0, 0, 0);
            sc[i] = __builtin_amdgcn_mfma_f32_16x16x32_bf16(a1, bq1, sc[i], 0, 0, 0);
        }

        float cm = -1e30f;
#pragma unroll
        for (int i = 0; i < 4; i++)
#pragma unroll
            for (int r = 0; r < 4; r++) {
                float s = sc[i][r] * 0.125f;
                sc[i][r] = s;
                cm = fmaxf(cm, s);
            }
        cm = fmaxf(cm, __shfl_xor(cm, 16));
        cm = fmaxf(cm, __shfl_xor(cm, 32));
        float mn = fmaxf(mo, cm);
        float alpha = __expf(mo - mn);
        float rs = 0.f;
#pragma unroll
        for (int i = 0; i < 4; i++) {
            bf16x4 pk;
#pragma unroll
            for (int r = 0; r < 4; r++) {
                float p = __expf(sc[i][r] - mn);
                rs += p;
                pk[r] = (bf16)p;
            }
            *(bf16x4*)&Ps[w][ln16 * QP + i * 16 + quad * 4] = pk;
        }
        rs += __shfl_xor(rs, 16);
        rs += __shfl_xor(rs, 32);
        l  = l * alpha + rs;
        mo = mn;
#pragma unroll
        for (int t = 0; t < 4; t++)
#pragma unroll
            for (int r = 0; r < 4; r++) O[t][r] *= alpha;

        bf16x8 bp0 = *(const bf16x8*)&Ps[w][ln16 * QP + quad * 8];
        bf16x8 bp1 = *(const bf16x8*)&Ps[w][ln16 * QP + 32 + quad * 8];
#pragma unroll
        for (int dt = 0; dt < 4; dt++) {
            bf16x8 a0 = *(const bf16x8*)&Vt[(dt * 16 + ln16) * QP + quad * 8];
            bf16x8 a1 = *(const bf16x8*)&Vt[(dt * 16 + ln16) * QP + 32 + quad * 8];
            O[dt] = __builtin_amdgcn_mfma_f32_16x16x32_bf16(a0, bp0, O[dt], 0, 0, 0);
            O[dt] = __builtin_amdgcn_mfma_f32_16x16x32_bf16(a1, bp1, O[dt], 0, 0, 0);
        }
    }

    {
        float inv = 1.0f / l;
#pragma unroll
        for (int dt = 0; dt < 4; dt++) {
            bf16x4 ov;
#pragma unroll
            for (int r = 0; r < 4; r++) ov[r] = (bf16)(O[dt][r] * inv);
            *(bf16x4*)&Qs[(w * 16 + ln16) * QP + dt * 16 + quad * 4] = ov;
        }
    }
    __syncthreads();
    {
        uint4 o0 = *(const uint4*)&Qs[r0 * QP + e0];
        uint4 o1 = *(const uint4*)&Qs[r0 * QP + e0 + 8];
        bf16* cg = ctx + ((long)(b * S_ + qt * 64 + r0)) * H_ + h * HD_;
        *(uint4*)&cg[e0]     = o0;
        *(uint4*)&cg[e0 + 8] = o1;
    }
}

// ---------------------------------------------------------------------------
// layernorm: one wave per row; bf16 in, fp32 out
// ---------------------------------------------------------------------------
__global__ __launch_bounds__(256) void ln_kernel(
    const bf16* __restrict__ y, const float* __restrict__ g,
    const float* __restrict__ be, float* __restrict__ out)
{
    const int lane = threadIdx.x & 63;
    const int w    = threadIdx.x >> 6;
    const long row = (long)blockIdx.x * 4 + w;
    const bf16* yr = y + row * H_;

    float x[12];
    float sum = 0.f, ss = 0.f;
#pragma unroll
    for (int j = 0; j < 12; j++) {
        x[j] = (float)yr[j * 64 + lane];
        sum += x[j];
        ss  += x[j] * x[j];
    }
#pragma unroll
    for (int m = 1; m < 64; m <<= 1) {
        sum += __shfl_xor(sum, m);
        ss  += __shfl_xor(ss, m);
    }
    const float mu  = sum * (1.0f / 768.0f);
    float var = ss * (1.0f / 768.0f) - mu * mu;
    const float rs = rsqrtf(fmaxf(var, 0.f) + 1e-12f);
#pragma unroll
    for (int j = 0; j < 12; j++) {
        int c = j * 64 + lane;
        out[row * H_ + c] = (x[j] - mu) * rs * g[c] + be[c];
    }
}

// ---------------------------------------------------------------------------
extern "C" void kernel_launch(void* const* d_in, const int* in_sizes, int n_in,
                              void* d_out, int out_size, void* d_ws, size_t ws_size,
                              hipStream_t stream)
{
    const float* hidden = (const float*)d_in[0];
    const float* ce     = (const float*)d_in[1];
    const int*   cc     = (const int*)d_in[2];
    const int*   vm     = (const int*)d_in[3];
    const float* Wd     = (const float*)d_in[4];
    const float* bd     = (const float*)d_in[5];
    const float* Wc     = (const float*)d_in[6];
    const float* bc     = (const float*)d_in[7];
    const float* Wq     = (const float*)d_in[8];
    const float* bq     = (const float*)d_in[9];
    const float* Wk     = (const float*)d_in[10];
    const float* bk     = (const float*)d_in[11];
    const float* Wv     = (const float*)d_in[12];
    const float* bv     = (const float*)d_in[13];
    const float* Wo     = (const float*)d_in[14];
    const float* bo     = (const float*)d_in[15];
    const float* lng    = (const float*)d_in[16];
    const float* lnb    = (const float*)d_in[17];

    // ---- workspace layout (bf16 elems; total ~102.8 MB) ----
    const long NE = (long)M_ * H_;
    bf16* ws   = (bf16*)d_ws;
    bf16* hbuf = ws;                          // gelu out / resid / y
    bf16* qkv  = ws + NE;                     // qb,kb,vb contiguous
    bf16* hbf  = qkv;                         // hbf over qb (dead before QKV writes)
    bf16* hcol = qkv + NE;                    // hcol over kb
    bf16* qb   = qkv;
    bf16* kb   = qkv + NE;
    bf16* vb   = qkv + 2 * NE;                // V^T layout [B,NH,HD,S]
    bf16* wpack = ws + 4 * NE;
    const bf16* Wd_b  = wpack;
    const bf16* Wc_b  = wpack + 589824;
    const bf16* Wq_b  = wpack + 1179648;
    const bf16* Wk_b  = wpack + 1769472;
    const bf16* Wv_b  = wpack + 2359296;
    const bf16* Wo_b  = wpack + 2949120;
    float* bqkv = (float*)(wpack + 3538944);
    bf16* ctx = (bf16*)d_out;                 // borrow d_out (dead before LN)

    cvt_x_kernel<<<2 * M_ * 96 / 256, 256, 0, stream>>>(hidden, ce, cc, vm, hbf, hcol);
    cvt_w_kernel<<<1730, 256, 0, stream>>>(Wd, Wc, Wq, Wk, Wv, Wo, bq, bk, bv, wpack, bqkv);

    dim3 g6(M_ / 128, 6);
    dim3 g18(M_ / 128, 18);
    gemm_bt<0><<<g6, 256, 0, stream>>>(hbf, hcol, Wd_b, Wc_b, bd, bc, nullptr, hbuf, 2 * H_, H_);
    gemm_bt<1><<<g18, 256, 0, stream>>>(hbuf, hbuf, Wq_b, Wq_b, bqkv, nullptr, nullptr, qkv, H_, 3 * H_);
    attn_kernel<<<3072, 256, 0, stream>>>(qb, kb, vb, ctx);
    gemm_bt<2><<<g6, 256, 0, stream>>>(ctx, ctx, Wo_b, Wo_b, bo, nullptr, hbuf, hbuf, H_, H_);
    ln_kernel<<<M_ / 4, 256, 0, stream>>>(hbuf, lng, lnb, (float*)d_out);
}

// Round 7
// 397.133 us; speedup vs baseline: 1.1022x; 1.1022x over previous
//
#include <hip/hip_runtime.h>
#include <hip/hip_bf16.h>
#include <math.h>
#include <stdint.h>

#define B_    32
#define S_    512
#define H_    768
#define NH_   12
#define HD_   64
#define NCOL_ 32
#define M_    (B_*S_)   // 16384

typedef __bf16 bf16;
typedef __bf16 bf16x8 __attribute__((ext_vector_type(8)));
typedef __bf16 bf16x4 __attribute__((ext_vector_type(4)));
typedef float  f32x4  __attribute__((ext_vector_type(4)));

// ---------------------------------------------------------------------------
// async global->LDS 16B copy (global_load_lds_dwordx4)
// ---------------------------------------------------------------------------
__device__ __forceinline__ void async_load16(const void* g, void* l) {
    __builtin_amdgcn_global_load_lds(
        (__attribute__((address_space(1))) unsigned int*)g,
        (__attribute__((address_space(3))) unsigned int*)l, 16, 0, 0);
}

// fp32 -> bf16x8 converting load (32B in)
__device__ __forceinline__ bf16x8 cvt8(const float* p) {
    const float4* fp = (const float4*)p;
    float4 x = fp[0], y = fp[1];
    bf16x8 r;
    r[0] = (bf16)x.x; r[1] = (bf16)x.y; r[2] = (bf16)x.z; r[3] = (bf16)x.w;
    r[4] = (bf16)y.x; r[5] = (bf16)y.y; r[6] = (bf16)y.z; r[7] = (bf16)y.w;
    return r;
}

// ---------------------------------------------------------------------------
// fused convert: hidden->hbf, gather->hcol, weights->wpack, qkv bias pack
// blocks [0,6144): hidden; [6144,12288): gather; [12288,14018): weights/bias
// ---------------------------------------------------------------------------
__global__ __launch_bounds__(256) void cvt_kernel(
    const float* __restrict__ hidden, const float* __restrict__ ce,
    const int* __restrict__ cc, const int* __restrict__ vm,
    const float* __restrict__ Wd, const float* __restrict__ Wc,
    const float* __restrict__ Wq, const float* __restrict__ Wk,
    const float* __restrict__ Wv, const float* __restrict__ Wo,
    const float* __restrict__ bq, const float* __restrict__ bk,
    const float* __restrict__ bv,
    bf16* __restrict__ hbf, bf16* __restrict__ hcol,
    bf16* __restrict__ wpack, float* __restrict__ bqkv)
{
    int blk = blockIdx.x;
    if (blk < 6144) {
        int id = blk * 256 + threadIdx.x;
        int row = id / 96, c = id - row * 96;
        *(bf16x8*)&hbf[(long)row * H_ + c * 8] = cvt8(hidden + (long)row * H_ + c * 8);
    } else if (blk < 12288) {
        int id = (blk - 6144) * 256 + threadIdx.x;
        int row = id / 96, c = id - row * 96;
        int b = row >> 9;
        int m = vm[row];
        bf16x8 val;
#pragma unroll
        for (int i = 0; i < 8; i++) val[i] = (bf16)0.0f;
        if (m > 0) {
            int col = m - 1;
            if (cc[b * NCOL_ + col] == 1)
                val = cvt8(ce + ((long)(b * NCOL_ + col)) * H_ + c * 8);
        }
        *(bf16x8*)&hcol[(long)row * H_ + c * 8] = val;
    } else {
        int id = (blk - 12288) * 256 + threadIdx.x;
        if (id < 442368) {
            const float* src;
            int r = id;
            if      (r < 73728)  { src = Wd; }
            else if (r < 147456) { src = Wc; r -= 73728; }
            else if (r < 221184) { src = Wq; r -= 147456; }
            else if (r < 294912) { src = Wk; r -= 221184; }
            else if (r < 368640) { src = Wv; r -= 294912; }
            else                 { src = Wo; r -= 368640; }
            *(bf16x8*)&wpack[(long)id * 8] = cvt8(src + (long)r * 8);
        } else if (id < 442656) {
            int j0 = (id - 442368) * 8;
#pragma unroll
            for (int i = 0; i < 8; i++) {
                int j = j0 + i;
                float v = (j < 768) ? bq[j] : (j < 1536) ? bk[j - 768] : bv[j - 1536];
                bqkv[j] = v;
            }
        }
    }
}

// ---------------------------------------------------------------------------
// GEMM C[m,n] = sum_k A[m,k]*Bw[n,k]  (+ epilogue per MODE), all bf16, lda=ldb=768
// BK=32, LDS DOUBLE-BUFFERED, ONE barrier per K-iter: prefetch for k+1 issued
// right after the barrier, drains at the NEXT barrier (compute phase in between
// hides the L2/HBM latency). A/B split at KSPLIT (mult of 32).
// MODE 0: gelu(acc + bias1 + bias2) -> [M,768] bf16
// MODE 1: acc + bias1 -> qkv: Q,K sections [B,NH,S,HD]; V section [B,NH,HD,S]
// MODE 2: acc + bias1 + resid -> [M,768] bf16 (in-place ok)
// ---------------------------------------------------------------------------
template<int MODE>
__global__ __launch_bounds__(256) void gemm_bt(
    const bf16* __restrict__ A0, const bf16* __restrict__ A1,
    const bf16* __restrict__ B0, const bf16* __restrict__ B1,
    const float* __restrict__ bias1, const float* __restrict__ bias2,
    const bf16* __restrict__ resid, bf16* __restrict__ out,
    int K, int KSPLIT)
{
    __shared__ __align__(16) bf16 As[2][128 * 32];
    __shared__ __align__(16) bf16 Bs[2][128 * 32];

    const int tid  = threadIdx.x;
    const int lane = tid & 63;
    const int wave = tid >> 6;
    const int wm   = wave & 1;
    const int wn   = wave >> 1;
    const int m0   = blockIdx.x * 128;
    const int n0   = blockIdx.y * 128;

    const int srow = tid >> 2;            // 0..63
    const int scol = (tid & 3) * 8;       // 0,8,16,24

    f32x4 acc[4][4];
    const f32x4 zero4 = {0.f, 0.f, 0.f, 0.f};
#pragma unroll
    for (int i = 0; i < 4; i++)
#pragma unroll
        for (int j = 0; j < 4; j++) acc[i][j] = zero4;

    const int a_off = (wm * 64 + (lane & 15)) * 32 + (lane >> 4) * 8;
    const int b_off = (wn * 64 + (lane & 15)) * 32 + (lane >> 4) * 8;

    auto stage = [&](int kk, int buf) {
        const bf16* ag = (kk < KSPLIT) ? A0 + kk : A1 + (kk - KSPLIT);
        const bf16* bg = (kk < KSPLIT) ? B0 + kk : B1 + (kk - KSPLIT);
        async_load16(ag + (long)(m0 + srow) * H_ + scol,      &As[buf][tid * 8]);
        async_load16(ag + (long)(m0 + 64 + srow) * H_ + scol, &As[buf][2048 + tid * 8]);
        async_load16(bg + (long)(n0 + srow) * H_ + scol,      &Bs[buf][tid * 8]);
        async_load16(bg + (long)(n0 + 64 + srow) * H_ + scol, &Bs[buf][2048 + tid * 8]);
    };

    stage(0, 0);
    int cur = 0;
    for (int k0 = 0; k0 < K; k0 += 32, cur ^= 1) {
        __syncthreads();   // buf[cur] drained+visible; all waves done reading buf[cur^1]
        if (k0 + 32 < K) stage(k0 + 32, cur ^ 1);   // drains at NEXT barrier

        bf16x8 af[4], bfr[4];
#pragma unroll
        for (int i = 0; i < 4; i++) af[i]  = *(const bf16x8*)(&As[cur][a_off + i * 512]);
#pragma unroll
        for (int j = 0; j < 4; j++) bfr[j] = *(const bf16x8*)(&Bs[cur][b_off + j * 512]);
#pragma unroll
        for (int i = 0; i < 4; i++)
#pragma unroll
            for (int j = 0; j < 4; j++)
                acc[i][j] = __builtin_amdgcn_mfma_f32_16x16x32_bf16(af[i], bfr[j], acc[i][j], 0, 0, 0);
    }

    const int c_r = (lane >> 4) * 4;
    const int c_c = lane & 15;

    int sec = 0;
    if (MODE == 1) sec = (n0 >= 1536) ? 2 : ((n0 >= 768) ? 1 : 0);
    bf16* dst = (MODE == 1) ? out + (long)sec * M_ * H_ : out;

#pragma unroll
    for (int j = 0; j < 4; j++) {
        const int col = n0 + wn * 64 + j * 16 + c_c;
        float bias = bias1[col];
        if (MODE == 0) bias += bias2[col];
#pragma unroll
        for (int i = 0; i < 4; i++) {
            if (MODE == 1 && sec == 2) {
                // V transposed [B,NH,HD,S]: 4 consecutive s -> one 8B store
                const int row0 = m0 + wm * 64 + i * 16 + c_r;   // 4-aligned
                int b = row0 >> 9, s = row0 & 511;
                int cs = col - 1536;
                int head = cs >> 6, d = cs & 63;
                bf16x4 pk;
#pragma unroll
                for (int r = 0; r < 4; r++) pk[r] = (bf16)(acc[i][j][r] + bias);
                *(bf16x4*)&dst[(((long)(b * NH_ + head)) * HD_ + d) * S_ + s] = pk;
            } else {
#pragma unroll
                for (int r = 0; r < 4; r++) {
                    const int row = m0 + wm * 64 + i * 16 + c_r + r;
                    float v = acc[i][j][r] + bias;
                    if (MODE == 0) {
                        v = 0.5f * v * (1.0f + erff(v * 0.70710678118654752f));
                        dst[(long)row * H_ + col] = (bf16)v;
                    } else if (MODE == 1) {
                        int b = row >> 9, s = row & 511;
                        int cs = col - sec * 768;
                        int head = cs >> 6, d = cs & 63;
                        dst[(((long)(b * NH_ + head)) * S_ + s) * HD_ + d] = (bf16)v;
                    } else {
                        v += (float)resid[(long)row * H_ + col];
                        dst[(long)row * H_ + col] = (bf16)v;
                    }
                }
            }
        }
    }
}

// ---------------------------------------------------------------------------
// flash attention, transposed-score form (unchanged from round 5).
// ---------------------------------------------------------------------------
#define QP 72   // LDS row stride (elems): 144 B, 16B-aligned

__global__ __launch_bounds__(256) void attn_kernel(
    const bf16* __restrict__ q, const bf16* __restrict__ k,
    const bf16* __restrict__ vt, bf16* __restrict__ ctx)
{
    __shared__ __align__(16) bf16 Qs[64 * QP];
    __shared__ __align__(16) bf16 Ks[64 * QP];
    __shared__ __align__(16) bf16 Vt[64 * QP];      // V^T chunk: [d][t]
    __shared__ __align__(16) bf16 Ps[4][16 * QP];   // per-wave P: [q][t]

    const int tid  = threadIdx.x;
    const int lane = tid & 63;
    const int w    = tid >> 6;
    const int quad = lane >> 4;
    const int ln16 = lane & 15;

    const int bid = blockIdx.x;
    const int qt  = bid / 384;          // qt-major: same g -> same XCD (384%8==0)
    const int g   = bid - qt * 384;
    const int b   = g / 12;
    const int h   = g - b * 12;
    const long base = ((long)(b * NH_ + h)) * S_ * HD_;

    const int r0 = tid >> 2;            // row 0..63
    const int e0 = (tid & 3) * 16;      // col elems 0,16,32,48

    {
        const bf16* qg = q + base + (long)qt * 64 * HD_;
        *(uint4*)&Qs[r0 * QP + e0]     = *(const uint4*)&qg[r0 * HD_ + e0];
        *(uint4*)&Qs[r0 * QP + e0 + 8] = *(const uint4*)&qg[r0 * HD_ + e0 + 8];
    }
    const bf16* kg = k  + base;
    const bf16* vg = vt + base;
    uint4 kr0 = *(const uint4*)&kg[r0 * HD_ + e0];
    uint4 kr1 = *(const uint4*)&kg[r0 * HD_ + e0 + 8];
    uint4 vr0 = *(const uint4*)&vg[(long)r0 * S_ + e0];
    uint4 vr1 = *(const uint4*)&vg[(long)r0 * S_ + e0 + 8];
    __syncthreads();

    const bf16x8 bq0 = *(const bf16x8*)&Qs[(w * 16 + ln16) * QP + quad * 8];
    const bf16x8 bq1 = *(const bf16x8*)&Qs[(w * 16 + ln16) * QP + 32 + quad * 8];

    f32x4 O[4];
    const f32x4 zero4 = {0.f, 0.f, 0.f, 0.f};
#pragma unroll
    for (int t = 0; t < 4; t++) O[t] = zero4;
    float mo = -1e30f, l = 0.f;

    for (int kc = 0; kc < 8; kc++) {
        __syncthreads();
        *(uint4*)&Ks[r0 * QP + e0]     = kr0;
        *(uint4*)&Ks[r0 * QP + e0 + 8] = kr1;
        *(uint4*)&Vt[r0 * QP + e0]     = vr0;
        *(uint4*)&Vt[r0 * QP + e0 + 8] = vr1;
        {
            int kcn = (kc < 7) ? kc + 1 : 7;
            kr0 = *(const uint4*)&kg[(long)kcn * 64 * HD_ + r0 * HD_ + e0];
            kr1 = *(const uint4*)&kg[(long)kcn * 64 * HD_ + r0 * HD_ + e0 + 8];
            vr0 = *(const uint4*)&vg[(long)r0 * S_ + kcn * 64 + e0];
            vr1 = *(const uint4*)&vg[(long)r0 * S_ + kcn * 64 + e0 + 8];
        }
        __syncthreads();

        f32x4 sc[4];
#pragma unroll
        for (int i = 0; i < 4; i++) {
            bf16x8 a0 = *(const bf16x8*)&Ks[(i * 16 + ln16) * QP + quad * 8];
            bf16x8 a1 = *(const bf16x8*)&Ks[(i * 16 + ln16) * QP + 32 + quad * 8];
            sc[i] = zero4;
            sc[i] = __builtin_amdgcn_mfma_f32_16x16x32_bf16(a0, bq0, sc[i], 0, 0, 0);
            sc[i] = __builtin_amdgcn_mfma_f32_16x16x32_bf16(a1, bq1, sc[i], 0, 0, 0);
        }

        float cm = -1e30f;
#pragma unroll
        for (int i = 0; i < 4; i++)
#pragma unroll
            for (int r = 0; r < 4; r++) {
                float s = sc[i][r] * 0.125f;
                sc[i][r] = s;
                cm = fmaxf(cm, s);
            }
        cm = fmaxf(cm, __shfl_xor(cm, 16));
        cm = fmaxf(cm, __shfl_xor(cm, 32));
        float mn = fmaxf(mo, cm);
        float alpha = __expf(mo - mn);
        float rs = 0.f;
#pragma unroll
        for (int i = 0; i < 4; i++) {
            bf16x4 pk;
#pragma unroll
            for (int r = 0; r < 4; r++) {
                float p = __expf(sc[i][r] - mn);
                rs += p;
                pk[r] = (bf16)p;
            }
            *(bf16x4*)&Ps[w][ln16 * QP + i * 16 + quad * 4] = pk;
        }
        rs += __shfl_xor(rs, 16);
        rs += __shfl_xor(rs, 32);
        l  = l * alpha + rs;
        mo = mn;
#pragma unroll
        for (int t = 0; t < 4; t++)
#pragma unroll
            for (int r = 0; r < 4; r++) O[t][r] *= alpha;

        bf16x8 bp0 = *(const bf16x8*)&Ps[w][ln16 * QP + quad * 8];
        bf16x8 bp1 = *(const bf16x8*)&Ps[w][ln16 * QP + 32 + quad * 8];
#pragma unroll
        for (int dt = 0; dt < 4; dt++) {
            bf16x8 a0 = *(const bf16x8*)&Vt[(dt * 16 + ln16) * QP + quad * 8];
            bf16x8 a1 = *(const bf16x8*)&Vt[(dt * 16 + ln16) * QP + 32 + quad * 8];
            O[dt] = __builtin_amdgcn_mfma_f32_16x16x32_bf16(a0, bp0, O[dt], 0, 0, 0);
            O[dt] = __builtin_amdgcn_mfma_f32_16x16x32_bf16(a1, bp1, O[dt], 0, 0, 0);
        }
    }

    {
        float inv = 1.0f / l;
#pragma unroll
        for (int dt = 0; dt < 4; dt++) {
            bf16x4 ov;
#pragma unroll
            for (int r = 0; r < 4; r++) ov[r] = (bf16)(O[dt][r] * inv);
            *(bf16x4*)&Qs[(w * 16 + ln16) * QP + dt * 16 + quad * 4] = ov;
        }
    }
    __syncthreads();
    {
        uint4 o0 = *(const uint4*)&Qs[r0 * QP + e0];
        uint4 o1 = *(const uint4*)&Qs[r0 * QP + e0 + 8];
        bf16* cg = ctx + ((long)(b * S_ + qt * 64 + r0)) * H_ + h * HD_;
        *(uint4*)&cg[e0]     = o0;
        *(uint4*)&cg[e0 + 8] = o1;
    }
}

// ---------------------------------------------------------------------------
// layernorm: one wave per row; bf16 in, fp32 out
// ---------------------------------------------------------------------------
__global__ __launch_bounds__(256) void ln_kernel(
    const bf16* __restrict__ y, const float* __restrict__ g,
    const float* __restrict__ be, float* __restrict__ out)
{
    const int lane = threadIdx.x & 63;
    const int w    = threadIdx.x >> 6;
    const long row = (long)blockIdx.x * 4 + w;
    const bf16* yr = y + row * H_;

    float x[12];
    float sum = 0.f, ss = 0.f;
#pragma unroll
    for (int j = 0; j < 12; j++) {
        x[j] = (float)yr[j * 64 + lane];
        sum += x[j];
        ss  += x[j] * x[j];
    }
#pragma unroll
    for (int m = 1; m < 64; m <<= 1) {
        sum += __shfl_xor(sum, m);
        ss  += __shfl_xor(ss, m);
    }
    const float mu  = sum * (1.0f / 768.0f);
    float var = ss * (1.0f / 768.0f) - mu * mu;
    const float rs = rsqrtf(fmaxf(var, 0.f) + 1e-12f);
#pragma unroll
    for (int j = 0; j < 12; j++) {
        int c = j * 64 + lane;
        out[row * H_ + c] = (x[j] - mu) * rs * g[c] + be[c];
    }
}

// ---------------------------------------------------------------------------
extern "C" void kernel_launch(void* const* d_in, const int* in_sizes, int n_in,
                              void* d_out, int out_size, void* d_ws, size_t ws_size,
                              hipStream_t stream)
{
    const float* hidden = (const float*)d_in[0];
    const float* ce     = (const float*)d_in[1];
    const int*   cc     = (const int*)d_in[2];
    const int*   vm     = (const int*)d_in[3];
    const float* Wd     = (const float*)d_in[4];
    const float* bd     = (const float*)d_in[5];
    const float* Wc     = (const float*)d_in[6];
    const float* bc     = (const float*)d_in[7];
    const float* Wq     = (const float*)d_in[8];
    const float* bq     = (const float*)d_in[9];
    const float* Wk     = (const float*)d_in[10];
    const float* bk     = (const float*)d_in[11];
    const float* Wv     = (const float*)d_in[12];
    const float* bv     = (const float*)d_in[13];
    const float* Wo     = (const float*)d_in[14];
    const float* bo     = (const float*)d_in[15];
    const float* lng    = (const float*)d_in[16];
    const float* lnb    = (const float*)d_in[17];

    // ---- workspace layout (bf16 elems; total ~102.8 MB) ----
    const long NE = (long)M_ * H_;
    bf16* ws   = (bf16*)d_ws;
    bf16* hbuf = ws;                          // gelu out / resid / y
    bf16* qkv  = ws + NE;                     // qb,kb,vb contiguous
    bf16* hbf  = qkv;                         // hbf over qb (dead before QKV writes)
    bf16* hcol = qkv + NE;                    // hcol over kb
    bf16* qb   = qkv;
    bf16* kb   = qkv + NE;
    bf16* vb   = qkv + 2 * NE;                // V^T layout [B,NH,HD,S]
    bf16* wpack = ws + 4 * NE;
    const bf16* Wd_b  = wpack;
    const bf16* Wc_b  = wpack + 589824;
    const bf16* Wq_b  = wpack + 1179648;
    const bf16* Wk_b  = wpack + 1769472;
    const bf16* Wv_b  = wpack + 2359296;
    const bf16* Wo_b  = wpack + 2949120;
    float* bqkv = (float*)(wpack + 3538944);
    bf16* ctx = (bf16*)d_out;                 // borrow d_out (dead before LN)

    cvt_kernel<<<14018, 256, 0, stream>>>(hidden, ce, cc, vm, Wd, Wc, Wq, Wk, Wv, Wo,
                                          bq, bk, bv, hbf, hcol, wpack, bqkv);

    dim3 g6(M_ / 128, 6);
    dim3 g18(M_ / 128, 18);
    gemm_bt<0><<<g6, 256, 0, stream>>>(hbf, hcol, Wd_b, Wc_b, bd, bc, nullptr, hbuf, 2 * H_, H_);
    gemm_bt<1><<<g18, 256, 0, stream>>>(hbuf, hbuf, Wq_b, Wq_b, bqkv, nullptr, nullptr, qkv, H_, 3 * H_);
    attn_kernel<<<3072, 256, 0, stream>>>(qb, kb, vb, ctx);
    gemm_bt<2><<<g6, 256, 0, stream>>>(ctx, ctx, Wo_b, Wo_b, bo, nullptr, hbuf, hbuf, H_, H_);
    ln_kernel<<<M_ / 4, 256, 0, stream>>>(hbuf, lng, lnb, (float*)d_out);
}